// Round 9
// baseline (176.310 us; speedup 1.0000x reference)
//
#include <hip/hip_runtime.h>
#include <math.h>

#define NBOX   4096
#define NTHR   1024
#define MAXDET 300
#define CAP    3968          // fallback path: boxes kept in LDS
#define NWORDS (NBOX / 32)
#define ROWW   64            // ull words per supmat row (4096 bits)
#define CTW    16            // col-tile width in words per supmat block

typedef unsigned long long ull;

__device__ __forceinline__ float clipf(float v, float hi) {
  return fminf(fmaxf(v, 0.0f), hi);
}

__device__ __forceinline__ float getimg(const int* img_i) {
  int iv = *img_i;
  return (iv > 0 && iv < (1 << 24)) ? (float)iv : __int_as_float(iv);
}

// =================== kernel A: keys + hybrid bitonic sort + fused prep ===================
struct SMA { ull skey[NBOX]; int vcount; };

__global__ __launch_bounds__(NTHR)
void sort_kernel(const float* __restrict__ scores,
                 const int*   __restrict__ labels,
                 const float* __restrict__ cls_w,
                 const float* __restrict__ boxes,
                 const int*   __restrict__ img_i,
                 int*    __restrict__ ws_sorted,
                 int*    __restrict__ ws_V,
                 int*    __restrict__ ws_done,
                 float4* __restrict__ obox,
                 float*  __restrict__ area,
                 int N)
{
  __shared__ SMA sm;
  const int b   = blockIdx.x;
  const int tid = threadIdx.x;
  const float* sc = scores + (size_t)b * N;
  const int*   lb = labels + (size_t)b * N;

  if (tid == 0) { sm.vcount = 0; ws_done[b] = 0; }   // reset per-call state
  for (int i = tid; i < NBOX; i += NTHR) {
    float s = sc[i];
    ull key = (ull)(0xFFFFFFFFu - (unsigned)i);
    if (s > 0.3f) {                       // SCORE_THRESHOLD, strict >
      float w = s * cls_w[lb[i]];
      unsigned ub = __float_as_uint(w);
      ub = (ub & 0x80000000u) ? ~ub : (ub | 0x80000000u);
      key |= ((ull)ub << 32);
    }
    sm.skey[i] = key;
  }
  __syncthreads();

  const int lane  = tid & 63;
  const int wbase = (tid >> 6) << 8;
  ull v0, v1, v2, v3;

  #define LOADV  { v0 = sm.skey[wbase      + lane]; v1 = sm.skey[wbase + 64 + lane]; \
                   v2 = sm.skey[wbase +128 + lane]; v3 = sm.skey[wbase +192 + lane]; }
  #define STOREV { sm.skey[wbase      + lane] = v0; sm.skey[wbase + 64 + lane] = v1; \
                   sm.skey[wbase +128 + lane] = v2; sm.skey[wbase +192 + lane] = v3; }
  #define CSWAP_REG(va, vb, eo) { int e_ = wbase + (eo) + lane;                      \
      if ((((e_) & k) == 0) ? ((va) < (vb)) : ((va) > (vb))) { ull t_ = (va); (va) = (vb); (vb) = t_; } }
  #define CSWAP_SHFL(vr, eo) { int e_ = wbase + (eo) + lane;                         \
      ull c_ = __shfl_xor((vr), j);                                                  \
      bool km_ = ((((e_) & k) == 0) == ((lane & j) == 0));                           \
      (vr) = km_ ? ((vr) > c_ ? (vr) : c_) : ((vr) < c_ ? (vr) : c_); }
  #define LOCALPHASES(jmax) {                                                        \
      for (int j = (jmax); j >= 1; j >>= 1) {                                        \
        if (j == 128)     { CSWAP_REG(v0, v2, 0);  CSWAP_REG(v1, v3, 64);  }         \
        else if (j == 64) { CSWAP_REG(v0, v1, 0);  CSWAP_REG(v2, v3, 128); }         \
        else { CSWAP_SHFL(v0, 0); CSWAP_SHFL(v1, 64); CSWAP_SHFL(v2, 128); CSWAP_SHFL(v3, 192); } } }

  LOADV;
  for (int k = 2; k <= 256; k <<= 1) { LOCALPHASES(k >> 1); }
  STOREV;
  __syncthreads();

  for (int k = 512; k <= NBOX; k <<= 1) {
    for (int j = k >> 1; j >= 256; j >>= 1) {
      for (int i = tid; i < NBOX; i += NTHR) {
        int l = i ^ j;
        if (l > i) {
          ull a = sm.skey[i], c = sm.skey[l];
          if (((i & k) == 0) ? (a < c) : (a > c)) { sm.skey[i] = c; sm.skey[l] = a; }
        }
      }
      __syncthreads();
    }
    LOADV;
    LOCALPHASES(128);
    STOREV;
    __syncthreads();
  }

  int* wsb = ws_sorted + (size_t)b * N;
  int vc = (int)((v0 >> 32) != 0) + (int)((v1 >> 32) != 0)
         + (int)((v2 >> 32) != 0) + (int)((v3 >> 32) != 0);
  atomicAdd(&sm.vcount, vc);

  // fused prep: gather clipped + class-offset boxes and areas in sorted order
  float fimg = getimg(img_i);
  float offs = fimg + 1.0f;
  const float4* bx4 = (const float4*)(boxes + (size_t)b * N * 4);
  float4* obx = obox + (size_t)b * NBOX;
  float*  oar = area + (size_t)b * NBOX;
  #define EMIT(vm, mo) {                                                   \
      int idx = wbase + (mo) + lane;                                       \
      unsigned orig = 0xFFFFFFFFu - (unsigned)((vm) & 0xFFFFFFFFull);      \
      wsb[idx] = (int)orig;                                                \
      float4 bb = bx4[orig];                                               \
      float off = (float)lb[orig] * offs;                                  \
      bb.x = clipf(bb.x, fimg) + off;                                      \
      bb.y = clipf(bb.y, fimg) + off;                                      \
      bb.z = clipf(bb.z, fimg) + off;                                      \
      bb.w = clipf(bb.w, fimg) + off;                                      \
      obx[idx] = bb;                                                       \
      oar[idx] = fmaxf(bb.z - bb.x, 0.0f) * fmaxf(bb.w - bb.y, 0.0f);      \
  }
  EMIT(v0, 0); EMIT(v1, 64); EMIT(v2, 128); EMIT(v3, 192);

  __syncthreads();
  if (tid == 0) ws_V[b] = sm.vcount;
}

// =================== kernel M: suppression matrix CHUNK ===================
__global__ __launch_bounds__(256)
void supmat_chunk(const float4* __restrict__ obox,
                  const float*  __restrict__ area,
                  const float*  __restrict__ nms_th,
                  const int*    __restrict__ ws_V,
                  const int*    __restrict__ ws_done,
                  ull* __restrict__ supmat,
                  int c1_tiles, int wlo)
{
  __shared__ float4 cbox[CTW * 64];
  __shared__ float  carea[CTW * 64];
  __shared__ float4 rbox[64];
  __shared__ float  rarea[64];

  const int b   = blockIdx.y;
  if (ws_done[b]) return;
  const int rt  = blockIdx.x % c1_tiles;
  const int g   = blockIdx.x / c1_tiles;
  const int tid = threadIdx.x;
  const int V   = ws_V[b];
  const int JW  = (V + 63) >> 6;

  const int wlo_g = wlo + g * CTW;
  const int w0 = (wlo_g > rt) ? wlo_g : rt;
  const int w1 = (wlo_g + CTW < JW) ? wlo_g + CTW : JW;
  if (rt >= JW || w0 >= w1) return;

  double xt = (double)(*nms_th);
  float  th = (float)(1.0 / (1.0 + exp(-xt)));

  const float4* ob = obox + (size_t)b * NBOX;
  const float*  ar = area + (size_t)b * NBOX;

  const int e1 = (w1 - w0) * 64;
  for (int e = tid; e < e1; e += 256) {
    cbox[e]  = ob[w0 * 64 + e];
    carea[e] = ar[w0 * 64 + e];
  }
  if (tid < 64) {
    rbox[tid]  = ob[rt * 64 + tid];
    rarea[tid] = ar[rt * 64 + tid];
  }
  __syncthreads();

  const int wave  = tid >> 6;
  const int lane  = tid & 63;
  const int rbase = wave * 16;
  ull* sb = supmat + (size_t)b * NBOX * ROWW;

  for (int w = w0; w < w1; ++w) {
    const float4 bj = cbox[(w - w0) * 64 + lane];
    const float  aj = carea[(w - w0) * 64 + lane];
    const int    j  = w * 64 + lane;
    #pragma unroll 4
    for (int rr = 0; rr < 16; ++rr) {
      const int i = rt * 64 + rbase + rr;
      if (i >= V) break;
      const float4 bi = rbox[rbase + rr];
      const float  ai = rarea[rbase + rr];
      float xx1 = fmaxf(bi.x, bj.x);
      float yy1 = fmaxf(bi.y, bj.y);
      float xx2 = fminf(bi.z, bj.z);
      float yy2 = fminf(bi.w, bj.w);
      float inter = fmaxf(xx2 - xx1, 0.0f) * fmaxf(yy2 - yy1, 0.0f);
      float denom = ai + aj;           // ((areas[i]+areas[j]) - inter) + 1e-9, ref order
      denom = denom - inter;
      denom = denom + 1e-9f;
      float iou = inter / denom;
      ull word = __ballot((iou > th) && (j > i));
      if (lane == 0) sb[(size_t)i * ROWW + w] = word;
    }
  }
}

// =================== kernel R: single-wave greedy resolve CHUNK (zero barriers) ===================
// State across chunks (in ws): done[b], total[b], kept[b][MAXDET].
template <int W>   // W = t1 - t0 words (16 or 32)
__global__ __launch_bounds__(64)
void resolve_chunk(const float* __restrict__ boxes,
                   const float* __restrict__ scores,
                   const int*   __restrict__ labels,
                   const int*   __restrict__ img_i,
                   float* __restrict__ out,
                   int B, int N,
                   const int* __restrict__ ws_sorted,
                   const int* __restrict__ ws_V,
                   const ull* __restrict__ supmat,
                   int* __restrict__ ws_done,
                   int* __restrict__ ws_total,
                   int* __restrict__ ws_kept,
                   int t0, int t1)
{
  __shared__ ull tbuf[2][64 * W];     // double-buffered tile block
  __shared__ ull kmask_sh[W];
  __shared__ int kept_sh[MAXDET];

  const int b = blockIdx.x;
  if (ws_done[b]) return;
  const int lane = threadIdx.x;       // single 64-lane wave
  const int V    = ws_V[b];
  const int JW   = (V + 63) >> 6;
  const ull* smat = supmat + (size_t)b * NBOX * ROWW;
  int* kg = ws_kept + (size_t)b * MAXDET;

  const int total_in = (t0 == 0) ? 0 : ws_total[b];

  // ---- catch-up (chunk>0): OR of prior kept rows, group-parallel + shfl reduce ----
  ull catchup = 0;
  if (t0 > 0) {
    const int G = 64 / W;             // 4 (W=16) or 2 (W=32)
    int g = lane / W, w = lane % W;
    ull acc = 0;
    for (int k = g; k < total_in; k += G)
      acc |= smat[(size_t)kg[k] * ROWW + t0 + w];
    acc |= __shfl_xor(acc, W);
    if (G == 4) acc |= __shfl_xor(acc, 2 * W);
    catchup = acc;                    // replicated; valid per word-lane
  }

  // alive: lane w (<W) owns global word t0+w
  ull alive = 0;
  if (lane < W) {
    int lo = (t0 + lane) * 64;
    if (V > lo) { int n = V - lo; alive = (n >= 64) ? ~0ull : ((1ull << n) - 1ull); }
    alive &= ~catchup;
  }

  int total = total_in;
  const int tmax = (t1 < JW) ? t1 : JW;
  const int cw   = (lane < W) ? lane : 0;

  // stage block t0 (64 rows x W words, swizzled); W elements per lane, coalesced
  if (t0 < tmax) {
    const ull* src = smat + (size_t)t0 * 64 * ROWW + t0;
    #pragma unroll
    for (int c = 0; c < W; ++c) {
      int e = lane + c * 64;
      int row = e / W, w = e % W;
      tbuf[0][row * W + (w ^ (row & (W - 1)))] = src[(size_t)row * ROWW + w];
    }
  }

  bool hit300 = false;
  int  tend   = t0;
  for (int t = t0; t < tmax; ++t) {
    const int cur = (t - t0) & 1;
    ull pr[W];
    const bool pf = (t + 1 < tmax);
    if (pf) {                          // issue next-block loads (independent, in flight)
      const ull* src = smat + (size_t)(t + 1) * 64 * ROWW + t0;
      #pragma unroll
      for (int c = 0; c < W; ++c) {
        int e = lane + c * 64;
        int row = e / W, w = e % W;
        pr[c] = src[(size_t)row * ROWW + w];
      }
    }
    ull aw = __shfl(alive, t - t0);
    ull keptmask = 0;
    if (aw) {
      // lane = row (t*64+lane) word t: boxes suppressed BY lane (bits m>lane)
      ull suprow = tbuf[cur][lane * W + ((t - t0) ^ (lane & (W - 1)))];
      // in-wave 64x64 bit transpose -> supbyT[lane] bit m = "lane suppressed by m"
      ull supbyT = 0;
      #pragma unroll
      for (int l = 0; l < 64; ++l) {
        ull bl = __ballot((suprow >> l) & 1ull);
        if (lane == l) supbyT = bl;
      }
      ull rem = aw;
      bool done = false;
      while (rem) {
        int l = __builtin_ctzll(rem);
        rem &= rem - 1;
        keptmask |= (1ull << l);
        ++total;
        if (total == MAXDET) { done = true; break; }
        ull su = __ballot((supbyT >> l) & 1ull);  // bit m = "m suppressed by kept l"
        rem &= ~su;
      }
      if (!done) {
        // apply kept rows to later words (pipelined independent ds_reads)
        ull a0 = 0, a1 = 0, a2 = 0, a3 = 0;
        ull km = keptmask;
        while (km) {
          int l = __builtin_ctzll(km); km &= km - 1;
          a0 |= tbuf[cur][l * W + (cw ^ (l & (W - 1)))];
          if (km) { l = __builtin_ctzll(km); km &= km - 1; a1 |= tbuf[cur][l * W + (cw ^ (l & (W - 1)))]; }
          if (km) { l = __builtin_ctzll(km); km &= km - 1; a2 |= tbuf[cur][l * W + (cw ^ (l & (W - 1)))]; }
          if (km) { l = __builtin_ctzll(km); km &= km - 1; a3 |= tbuf[cur][l * W + (cw ^ (l & (W - 1)))]; }
        }
        if (lane < W && (t0 + lane) > t) alive &= ~((a0 | a1) | (a2 | a3));
      } else {
        hit300 = true;                 // wave-uniform
      }
    }
    if (lane == 0) kmask_sh[t - t0] = keptmask;
    tend = t + 1;
    if (hit300) break;
    if (pf) {
      #pragma unroll
      for (int c = 0; c < W; ++c) {
        int e = lane + c * 64;
        int row = e / W, w = e % W;
        tbuf[cur ^ 1][row * W + (w ^ (row & (W - 1)))] = pr[c];
      }
    }
  }

  // ---- expand kept masks -> kept_sh (lane per tile, prefix scan) ----
  const int ntiles = tend - t0;
  {
    ull km = (lane < ntiles) ? kmask_sh[lane] : 0ull;
    int pc = __popcll(km);
    int incl = pc;
    #pragma unroll
    for (int s = 1; s < 64; s <<= 1) {
      int v = __shfl_up(incl, s);
      if (lane >= s) incl += v;
    }
    int base = total_in + incl - pc;
    while (km) {
      int l = __builtin_ctzll(km);
      km &= km - 1;
      kept_sh[base++] = (t0 + lane) * 64 + l;
    }
  }

  const int K = total;                 // wave-uniform
  for (int rI = total_in + lane; rI < K; rI += 64) kg[rI] = kept_sh[rI];

  const bool finished = hit300 || (t1 >= JW);
  if (!finished) {
    if (lane == 0) ws_total[b] = K;
    return;
  }
  if (lane == 0) ws_done[b] = 1;

  // ---- outputs ----
  float fimg = getimg(img_i);
  const float* bx = boxes  + (size_t)b * N * 4;
  const float* sc = scores + (size_t)b * N;
  const int*   lb = labels + (size_t)b * N;
  const int*   so = ws_sorted + (size_t)b * N;

  float4* obx = (float4*)out;
  float*  osc = out + (size_t)B * MAXDET * 4;
  float*  olb = osc + (size_t)B * MAXDET;
  float*  ovl = olb + (size_t)B * MAXDET;
  for (int rI = lane; rI < MAXDET; rI += 64) {
    size_t slot = (size_t)b * MAXDET + rI;
    if (rI < K) {
      int i    = (rI < total_in) ? kg[rI] : kept_sh[rI];
      int orig = so[i];
      float4 bb = ((const float4*)bx)[orig];
      bb.x = clipf(bb.x, fimg);
      bb.y = clipf(bb.y, fimg);
      bb.z = clipf(bb.z, fimg);
      bb.w = clipf(bb.w, fimg);
      obx[slot] = bb;
      osc[slot] = sc[orig];
      olb[slot] = (float)lb[orig];
      ovl[slot] = 1.0f;
    } else {
      obx[slot] = make_float4(0.f, 0.f, 0.f, 0.f);
      osc[slot] = 0.0f;
      olb[slot] = 0.0f;
      ovl[slot] = 0.0f;
    }
  }
}

// =================== fallback kernel (round-2 path, used if ws too small) ===================
struct SMB {
  float4       obox[CAP];
  unsigned int keepw[NWORDS];
  int          kept_pos[MAXDET];
  int          scal[4];
};

__global__ __launch_bounds__(NTHR)
void nms_kernel(const float* __restrict__ boxes,
                const float* __restrict__ scores,
                const int*   __restrict__ labels,
                const float* __restrict__ nms_th,
                const float* __restrict__ cls_w,
                const int*   __restrict__ img_i,
                float* __restrict__ out,
                int B, int N,
                const int* __restrict__ ws_sorted,
                const int* __restrict__ ws_V,
                float4* __restrict__ ws_ovf)
{
  __shared__ SMB sm;
  const int b    = blockIdx.x;
  const int tid  = threadIdx.x;

  const float* bx = boxes  + (size_t)b * N * 4;
  const float* sc = scores + (size_t)b * N;
  const int*   lb = labels + (size_t)b * N;
  const int*   so = ws_sorted + (size_t)b * N;

  float fimg = getimg(img_i);
  float off_scale = fimg + 1.0f;
  double xt = (double)(*nms_th);
  float  th = (float)(1.0 / (1.0 + exp(-xt)));

  const int V = ws_V[b];
  if (tid < 4) sm.scal[tid] = 0;

  for (int m = 0; m < 4; ++m) {
    int i = tid + m * NTHR;
    int orig = so[i];
    float4 bb = ((const float4*)bx)[orig];
    float off = (float)lb[orig] * off_scale;
    bb.x = clipf(bb.x, fimg) + off;
    bb.y = clipf(bb.y, fimg) + off;
    bb.z = clipf(bb.z, fimg) + off;
    bb.w = clipf(bb.w, fimg) + off;
    if (i < CAP) sm.obox[i] = bb;
    else         ws_ovf[(size_t)b * (NBOX - CAP) + (i - CAP)] = bb;
  }
  for (int w = tid; w < NWORDS; w += NTHR) {
    int lo = w * 32;
    unsigned val;
    if      (V >= lo + 32) val = 0xFFFFFFFFu;
    else if (V <= lo)      val = 0u;
    else                   val = (1u << (V - lo)) - 1u;
    sm.keepw[w] = val;
  }
  __syncthreads();

  const int nt = (V + 63) >> 6;
  int TR = 0;
  for (int t = 0; t < nt; ++t) {
    if (tid < 64) {
      int i0 = t * 64;
      int me = i0 + tid;
      float4 bb = (me < CAP) ? sm.obox[me]
                             : ws_ovf[(size_t)b * (NBOX - CAP) + (me - CAP)];
      float arJ = fmaxf(bb.z - bb.x, 0.0f) * fmaxf(bb.w - bb.y, 0.0f);
      ull supby = 0;
      for (int l = 0; l < 64; ++l) {
        int i = i0 + l;
        float4 bi = (i < CAP) ? sm.obox[i]
                              : ws_ovf[(size_t)b * (NBOX - CAP) + (i - CAP)];
        float ai = fmaxf(bi.z - bi.x, 0.0f) * fmaxf(bi.w - bi.y, 0.0f);
        float xx1 = fmaxf(bi.x, bb.x);
        float yy1 = fmaxf(bi.y, bb.y);
        float xx2 = fminf(bi.z, bb.z);
        float yy2 = fminf(bi.w, bb.w);
        float inter = fmaxf(xx2 - xx1, 0.0f) * fmaxf(yy2 - yy1, 0.0f);
        float denom = ai + arJ;
        denom = denom - inter;
        denom = denom + 1e-9f;
        float iou = inter / denom;
        if (iou > th) supby |= (1ull << l);
      }
      ull alive = ((ull)sm.keepw[2 * t + 1] << 32) | sm.keepw[2 * t];
      ull rem = alive;
      while (rem) {
        int l = __builtin_ctzll(rem);
        rem &= rem - 1;
        ull sup = __ballot((supby >> l) & 1ull);
        sup &= ((~1ull) << l);
        sup &= alive;
        alive &= ~sup;
        rem   &= ~sup;
      }
      if (tid == 0) {
        sm.keepw[2 * t]     = (unsigned)alive;
        sm.keepw[2 * t + 1] = (unsigned)(alive >> 32);
        atomicAdd(&sm.scal[1], __builtin_popcountll(alive));
      }
    }
    __syncthreads();
    TR = t + 1;
    if (sm.scal[1] >= MAXDET) break;

    int jstart = (t + 1) * 64;
    if (jstart < V) {
      ull alive = ((ull)sm.keepw[2 * t + 1] << 32) | sm.keepw[2 * t];
      if (alive) {
        for (int j = jstart + tid; j < V; j += NTHR) {
          unsigned wj = sm.keepw[j >> 5];
          if (!((wj >> (j & 31)) & 1u)) continue;
          float4 bj = (j < CAP) ? sm.obox[j]
                                : ws_ovf[(size_t)b * (NBOX - CAP) + (j - CAP)];
          float aj = fmaxf(bj.z - bj.x, 0.0f) * fmaxf(bj.w - bj.y, 0.0f);
          ull rem = alive;
          bool suppressed = false;
          while (rem) {
            int l = __builtin_ctzll(rem);
            rem &= rem - 1;
            int i = t * 64 + l;
            float4 bi = (i < CAP) ? sm.obox[i]
                                  : ws_ovf[(size_t)b * (NBOX - CAP) + (i - CAP)];
            float ai = fmaxf(bi.z - bi.x, 0.0f) * fmaxf(bi.w - bi.y, 0.0f);
            float xx1 = fmaxf(bi.x, bj.x);
            float yy1 = fmaxf(bi.y, bj.y);
            float xx2 = fminf(bi.z, bj.z);
            float yy2 = fminf(bi.w, bj.w);
            float inter = fmaxf(xx2 - xx1, 0.0f) * fmaxf(yy2 - yy1, 0.0f);
            float denom = ai + aj;
            denom = denom - inter;
            denom = denom + 1e-9f;
            float iou = inter / denom;
            if (iou > th) { suppressed = true; break; }
          }
          if (suppressed) atomicAnd(&sm.keepw[j >> 5], ~(1u << (j & 31)));
        }
      }
    }
    __syncthreads();
  }

  if (tid < NWORDS && tid >= TR * 2) sm.keepw[tid] = 0;
  __syncthreads();
  if (tid == 0) {
    int r = 0;
    for (int w = 0; w < NWORDS && r < MAXDET; ++w) {
      unsigned bits = sm.keepw[w];
      while (bits && r < MAXDET) {
        int l = __builtin_ctz(bits);
        bits &= bits - 1;
        sm.kept_pos[r++] = w * 32 + l;
      }
    }
    sm.scal[3] = r;
  }
  __syncthreads();
  const int K = sm.scal[3];

  float4* obx = (float4*)out;
  float*  osc = out + (size_t)B * MAXDET * 4;
  float*  olb = osc + (size_t)B * MAXDET;
  float*  ovl = olb + (size_t)B * MAXDET;
  for (int r = tid; r < MAXDET; r += NTHR) {
    size_t slot = (size_t)b * MAXDET + r;
    if (r < K) {
      int i    = sm.kept_pos[r];
      int orig = so[i];
      float4 bb = ((const float4*)bx)[orig];
      bb.x = clipf(bb.x, fimg);
      bb.y = clipf(bb.y, fimg);
      bb.z = clipf(bb.z, fimg);
      bb.w = clipf(bb.w, fimg);
      obx[slot] = bb;
      osc[slot] = sc[orig];
      olb[slot] = (float)lb[orig];
      ovl[slot] = 1.0f;
    } else {
      obx[slot] = make_float4(0.f, 0.f, 0.f, 0.f);
      osc[slot] = 0.0f;
      olb[slot] = 0.0f;
      ovl[slot] = 0.0f;
    }
  }
}

extern "C" void kernel_launch(void* const* d_in, const int* in_sizes, int n_in,
                              void* d_out, int out_size, void* d_ws, size_t ws_size,
                              hipStream_t stream) {
  const float* boxes      = (const float*)d_in[0];
  const float* scores     = (const float*)d_in[1];
  const int*   labels     = (const int*)d_in[2];
  const float* nms_thresh = (const float*)d_in[3];
  const float* cls_w      = (const float*)d_in[4];
  const int*   img_sz     = (const int*)d_in[5];

  int B = out_size / (MAXDET * 7);
  int N = in_sizes[1] / B;               // 4096

  // ws layout
  size_t sz_sorted = (size_t)B * N * 4;
  size_t off_V     = sz_sorted;
  size_t off_obox  = sz_sorted + 1024;
  size_t sz_obox   = (size_t)B * NBOX * 16;
  size_t off_area  = off_obox + sz_obox;
  size_t sz_area   = (size_t)B * NBOX * 4;
  size_t off_done  = (off_area + sz_area + 255) & ~(size_t)255;
  size_t off_total = off_done + (size_t)B * 4;
  size_t off_kept  = off_total + (size_t)B * 4;
  size_t off_sup   = (off_kept + (size_t)B * MAXDET * 4 + 255) & ~(size_t)255;
  size_t sz_sup    = (size_t)B * NBOX * ROWW * 8;   // 32 MiB at B=16
  size_t need_fast = off_sup + sz_sup;

  int*    ws_sorted = (int*)d_ws;
  int*    ws_V      = (int*)((char*)d_ws + off_V);
  int*    ws_done   = (int*)((char*)d_ws + off_done);
  float4* obox      = (float4*)((char*)d_ws + off_obox);
  float*  area      = (float*)((char*)d_ws + off_area);

  sort_kernel<<<dim3(B), dim3(NTHR), 0, stream>>>(
      scores, labels, cls_w, boxes, img_sz,
      ws_sorted, ws_V, ws_done, obox, area, N);

  if (ws_size >= need_fast && N == NBOX) {
    int* ws_total = (int*)((char*)d_ws + off_total);
    int* ws_kept  = (int*)((char*)d_ws + off_kept);
    ull* supmat   = (ull*)((char*)d_ws + off_sup);

    // chunk 0: tiles [0,16)
    supmat_chunk<<<dim3(16, B), dim3(256), 0, stream>>>(
        obox, area, nms_thresh, ws_V, ws_done, supmat, 16, 0);
    resolve_chunk<16><<<dim3(B), dim3(64), 0, stream>>>(
        boxes, scores, labels, img_sz, (float*)d_out, B, N,
        ws_sorted, ws_V, supmat, ws_done, ws_total, ws_kept, 0, 16);

    // chunk 1: tiles [16,32)
    supmat_chunk<<<dim3(32, B), dim3(256), 0, stream>>>(
        obox, area, nms_thresh, ws_V, ws_done, supmat, 32, 16);
    resolve_chunk<16><<<dim3(B), dim3(64), 0, stream>>>(
        boxes, scores, labels, img_sz, (float*)d_out, B, N,
        ws_sorted, ws_V, supmat, ws_done, ws_total, ws_kept, 16, 32);

    // chunk 2: tiles [32,64)
    supmat_chunk<<<dim3(128, B), dim3(256), 0, stream>>>(
        obox, area, nms_thresh, ws_V, ws_done, supmat, 64, 32);
    resolve_chunk<32><<<dim3(B), dim3(64), 0, stream>>>(
        boxes, scores, labels, img_sz, (float*)d_out, B, N,
        ws_sorted, ws_V, supmat, ws_done, ws_total, ws_kept, 32, 64);
  } else {
    float4* ws_ovf = (float4*)((char*)d_ws + off_done + 1024);
    nms_kernel<<<dim3(B), dim3(NTHR), 0, stream>>>(boxes, scores, labels,
                                                   nms_thresh, cls_w, img_sz,
                                                   (float*)d_out, B, N,
                                                   ws_sorted, ws_V, ws_ovf);
  }
}